// Round 3
// baseline (221.506 us; speedup 1.0000x reference)
//
#include <hip/hip_runtime.h>
#include <hip/hip_bf16.h>
#include <stdint.h>

// WarpNet: conv_bn_relu(512->384 combined) -> window-distance softmax warp -> 1x1 conv -> log_softmax

typedef float v4f __attribute__((ext_vector_type(4)));
typedef __bf16 v8bf __attribute__((ext_vector_type(8)));
typedef unsigned short u16;
typedef unsigned int u32;
typedef u16 u16x8 __attribute__((ext_vector_type(8)));

// ---------------- workspace layout (bytes) ----------------
constexpr size_t XH_OFF  = 0;                                  // padded NHWC input bf16 [4][66][66][512]
constexpr size_t XH_BYTES = (size_t)4*66*66*512*2;
constexpr size_t WT_OFF  = XH_OFF + XH_BYTES;                  // weight FRAGMENTS bf16 [9 pos][16 cc][24 ocb][64 lane][8]
constexpr size_t WT_BYTES = (size_t)9*16*24*64*8*2;
constexpr size_t FS_OFF  = WT_OFF + WT_BYTES;                  // clip_emb_s NHWC bf16 [4][68][68][256] (pad2)
constexpr size_t FS_BYTES = (size_t)4*68*68*256*2;
constexpr size_t F2_OFF  = FS_OFF + FS_BYTES;                  // clip_emb2 NHWC f32 [4][68][68][128] (pad2)
constexpr size_t F2_BYTES = (size_t)4*68*68*128*4;
constexpr size_t Y2_OFF  = F2_OFF + F2_BYTES;                  // y2 f32 [2][68][68] (border 1e20, interior atomics)
constexpr size_t Y2_BYTES = (size_t)2*68*68*4;
constexpr size_t FEA_OFF = Y2_OFF + Y2_BYTES;                  // final_fea bf16 [2][4096][256]
constexpr size_t FEA_BYTES = (size_t)2*4096*256*2;
constexpr size_t WL_OFF  = FEA_OFF + FEA_BYTES;                // last_W bf16 [128][256]
constexpr size_t WL_BYTES = (size_t)128*256*2;
constexpr size_t SC_OFF  = WL_OFF + WL_BYTES;                  // sc[384], bi[384] f32
constexpr size_t WS_TOTAL = SC_OFF + 768*4;

__device__ __forceinline__ float bf2f(u16 h) { return __uint_as_float(((u32)h) << 16); }
__device__ __forceinline__ u16 f2bf(float f) {
  u32 u = __float_as_uint(f);
  return (u16)((u + 0x7fffu + ((u >> 16) & 1u)) >> 16);
}

__device__ __forceinline__ void gld16(const void* g, const void* l) {
  __builtin_amdgcn_global_load_lds(
      (const __attribute__((address_space(1))) void*)(uintptr_t)g,
      (__attribute__((address_space(3))) void*)(u32)(uintptr_t)l,
      16, 0, 0);
}

// ---------------- init: borders, Y2, Wl, sc/bi (fused) ----------------
__global__ void k_init(const float* __restrict__ eg, const float* __restrict__ eb,
                       const float* __restrict__ em, const float* __restrict__ ev,
                       const float* __restrict__ e2g, const float* __restrict__ e2b,
                       const float* __restrict__ e2m, const float* __restrict__ e2v,
                       const float* __restrict__ lw,
                       u16* __restrict__ Xh, u16* __restrict__ Fs, float* __restrict__ F2,
                       float* __restrict__ Y2, u16* __restrict__ Wl,
                       float* __restrict__ sc, float* __restrict__ bi) {
  const u32 N0 = 4u * 260u * 64u;   // Xh border u16x8 chunks
  const u32 N1 = 4u * 528u * 32u;   // Fs border u16x8 chunks
  const u32 N2 = 4u * 528u * 32u;   // F2 border float4 chunks
  const u32 N3 = 2u * 68u * 68u;    // Y2 floats
  const u32 N4 = 4096u;             // Wl u16x8 chunks
  const u32 N5 = 384u;              // sc/bi
  const u32 TOT = N0 + N1 + N2 + N3 + N4 + N5;
  const u16x8 z8 = {0,0,0,0,0,0,0,0};
  for (u32 i = blockIdx.x * 256u + threadIdx.x; i < TOT; i += gridDim.x * 256u) {
    if (i < N0) {
      const u32 img = i / (260u * 64u);
      const u32 rem = i - img * (260u * 64u);
      const u32 r = rem >> 6, ch8 = rem & 63u;
      u32 prow, pcol;
      if (r < 132u) { prow = (r >= 66u) ? 65u : 0u; pcol = r - ((r >= 66u) ? 66u : 0u); }
      else { const u32 rr = r - 132u; prow = 1u + (rr >> 1); pcol = (rr & 1u) * 65u; }
      *(u16x8*)(Xh + ((size_t)((img * 66u + prow) * 66u + pcol)) * 512u + ch8 * 8u) = z8;
    } else if (i < N0 + N1 + N2) {
      const bool isF2 = (i >= N0 + N1);
      const u32 j = isF2 ? (i - N0 - N1) : (i - N0);
      const u32 img = j / (528u * 32u);
      const u32 rem = j - img * (528u * 32u);
      const u32 r = rem >> 5, cg = rem & 31u;
      u32 prow, pcol;
      if (r < 272u) { const u32 q = r / 68u; prow = (q < 2u) ? q : q + 64u; pcol = r - q * 68u; }
      else { const u32 rr = r - 272u; prow = 2u + (rr >> 2); const u32 c = rr & 3u; pcol = (c < 2u) ? c : c + 64u; }
      if (isF2) {
        const float4 zf = {0.f, 0.f, 0.f, 0.f};
        *(float4*)(F2 + ((size_t)((img * 68u + prow) * 68u + pcol)) * 128u + cg * 4u) = zf;
      } else {
        *(u16x8*)(Fs + ((size_t)((img * 68u + prow) * 68u + pcol)) * 256u + cg * 8u) = z8;
      }
    } else if (i < N0 + N1 + N2 + N3) {
      const u32 j = i - N0 - N1 - N2;
      const u32 n = j / 4624u, rc = j - n * 4624u;
      const u32 rr = rc / 68u, cc = rc - rr * 68u;
      const bool interior = (rr >= 2u && rr < 66u && cc >= 2u && cc < 66u);
      Y2[j] = interior ? 0.f : 1e20f;
    } else if (i < N0 + N1 + N2 + N3 + N4) {
      const u32 j = i - N0 - N1 - N2 - N3;
      const u32 row = j >> 5, c8 = (j & 31u) * 8u;
      u16x8 o;
      #pragma unroll
      for (int k = 0; k < 8; ++k) o[k] = (row < 124u) ? f2bf(lw[row * 256u + c8 + k]) : (u16)0;
      *(u16x8*)(Wl + (size_t)row * 256u + c8) = o;
    } else {
      const u32 id = i - N0 - N1 - N2 - N3 - N4;
      float g, b, m, v;
      if (id < 256u) { g = eg[id]; b = eb[id]; m = em[id]; v = ev[id]; }
      else { const u32 q = id - 256u; g = e2g[q]; b = e2b[q]; m = e2m[q]; v = e2v[q]; }
      const float s = g / sqrtf(v + 1e-5f);
      sc[id] = s;
      bi[id] = b - m * s;
    }
  }
}

// ---------------- NCHW f32 -> padded NHWC bf16 ----------------
__global__ __launch_bounds__(256) void k_prep_x(const float* __restrict__ X, u16* __restrict__ Xh) {
  __shared__ __align__(16) float tile[64 * 65];
  const int tid = threadIdx.x;
  const int n = blockIdx.x >> 7;
  const int rem = blockIdx.x & 127;
  const int h = rem >> 1, chalf = rem & 1;
  const int wq = tid >> 6, wcol = tid & 63;
  #pragma unroll 1
  for (int it = 0; it < 4; ++it) {
    const int c0 = chalf * 256 + it * 64;
    __syncthreads();
    #pragma unroll
    for (int i = 0; i < 16; ++i) {
      const int cl = i * 4 + wq;
      tile[cl * 65 + wcol] = X[((size_t)(n * 512 + c0 + cl)) * 4096 + h * 64 + wcol];
    }
    __syncthreads();
    const int w = tid >> 2, cg = tid & 3;
    u16x8 a, b;
    #pragma unroll
    for (int j = 0; j < 8; ++j) a[j] = f2bf(tile[(cg * 16 + j) * 65 + w]);
    #pragma unroll
    for (int j = 0; j < 8; ++j) b[j] = f2bf(tile[(cg * 16 + 8 + j) * 65 + w]);
    u16* dst = Xh + ((size_t)((n * 66 + h + 1) * 66 + (w + 1))) * 512 + c0 + cg * 16;
    *(u16x8*)dst = a;
    *((u16x8*)dst + 1) = b;
  }
}

// ---------------- weights [oc][512][3][3] f32 -> fragment layout [pos][cc][ocb][lane][8] bf16 ----------------
__global__ __launch_bounds__(256) void k_prep_w(const float* __restrict__ embW, const float* __restrict__ emb2W,
                                                u16* __restrict__ Wf) {
  __shared__ float row[4608];
  const int oc = blockIdx.x;
  const int tid = threadIdx.x;
  const float* src = (oc < 256) ? (embW + (size_t)oc * 4608) : (emb2W + (size_t)(oc - 256) * 4608);
  for (int i = tid; i < 4608; i += 256) row[i] = src[i];
  __syncthreads();
  const int cc = tid >> 4;             // ch = 2*tid: cc = ch>>5
  const int slot = (tid >> 2) & 3;     // (ch>>3)&3
  const int e = 2 * (tid & 3);         // ch&7
  const int r = oc & 15, ocb = oc >> 4;
  #pragma unroll
  for (int pos = 0; pos < 9; ++pos) {
    const u32 pk = (u32)f2bf(row[(2 * tid) * 9 + pos]) | ((u32)f2bf(row[(2 * tid + 1) * 9 + pos]) << 16);
    *(u32*)(Wf + ((size_t)((pos * 16 + cc) * 24 + ocb)) * 512 + (slot * 16 + r) * 8 + e) = pk;
  }
}

// ---------------- implicit-GEMM conv + BN + ReLU (+ y2 atomics) ----------------
// grid 384: octile(3:128oc) x n(4) x pixtile(32:2 rows). 4 waves 2x2 -> wave = 64oc x 64px.
// A (weights) from GLOBAL as pre-arranged fragments (L2-resident). LDS holds only B (dbuf).
// B swizzle: LDS slot s holds global slot s ^ ((col>>1)&3)  [conflict-free ds_read_b128].
__global__ __launch_bounds__(256) void k_conv(const u16* __restrict__ Xh, const u16* __restrict__ Wf,
                                              const float* __restrict__ sc, const float* __restrict__ bi,
                                              float* __restrict__ out2, float* __restrict__ F2,
                                              u16* __restrict__ Fs, float* __restrict__ Y2) {
  __shared__ __align__(16) char lds[34816];  // B: 2x16896 | sc/bi @33792 (1KB). Epilogue T overlays [0,32768).
  const int tid = threadIdx.x;
  const int wvi = tid >> 6, lane = tid & 63;
  const int octile = blockIdx.x >> 7;
  const int rest = blockIdx.x & 127;
  const int n = rest >> 5, pt = rest & 31;
  const int h0 = pt * 2;
  const int ochalf = wvi >> 1, prow = wvi & 1;

  float* scl = (float*)(lds + 33792);
  float* bil = scl + 128;
  if (tid < 128) { scl[tid] = sc[octile * 128 + tid]; bil[tid] = bi[octile * 128 + tid]; }

  // B staging sources: 1056 chunks (264 cols x 4 slots), swizzled source slot
  const u16* xbase = Xh + (size_t)n * 66 * 66 * 512;
  int bofs[5];
  #pragma unroll
  for (int k = 0; k < 5; ++k) {
    const int idx = k * 256 + tid;
    if (idx < 1056) {
      const int col = idx >> 2;
      const int ssrc = (idx & 3) ^ ((col >> 1) & 3);
      const int imgrow = col / 66, c = col - imgrow * 66;
      bofs[k] = ((h0 + imgrow) * 66 + c) * 512 + ssrc * 8;
    } else bofs[k] = 0;
  }

  auto stageB = [&](int cc, int buf) {
    char* base = lds + buf * 16896;
    #pragma unroll
    for (int k = 0; k < 4; ++k)
      gld16(xbase + bofs[k] + cc * 32, base + k * 4096 + tid * 16);
    if (tid < 32) gld16(xbase + bofs[4] + cc * 32, base + 16384 + tid * 16);
  };

  const int ocb0 = octile * 8 + ochalf * 4;
  const int lane8 = lane * 8;
  auto loadA = [&](int pos, int cc, int mt) {
    return *(const v8bf*)(Wf + ((size_t)((pos * 16 + cc) * 24 + ocb0 + mt)) * 512 + lane8);
  };
  const int rbB = prow * 66 + (lane & 15);
  const int slotb = lane >> 4;
  auto readB = [&](int buf, int rb) {
    return *(const v8bf*)(lds + buf * 16896 + rb * 64 + (((slotb ^ ((rb >> 1) & 3))) << 4));
  };

  v4f acc[4][4];
  #pragma unroll
  for (int mt = 0; mt < 4; ++mt)
    #pragma unroll
    for (int nt = 0; nt < 4; ++nt) acc[mt][nt] = (v4f){0.f, 0.f, 0.f, 0.f};

  int buf = 0;
  stageB(0, 0);
  v8bf ac[4];
  #pragma unroll
  for (int mt = 0; mt < 4; ++mt) ac[mt] = loadA(0, 0, mt);
  __syncthreads();

  #pragma unroll 1
  for (int cc = 0; cc < 16; ++cc) {
    #pragma unroll
    for (int pos = 0; pos < 9; ++pos) {
      const int ky = pos / 3, kx = pos % 3;
      if (pos == 5 && cc < 15) stageB(cc + 1, buf ^ 1);
      v8bf an[4];
      if (pos < 8) {
        #pragma unroll
        for (int mt = 0; mt < 4; ++mt) an[mt] = loadA(pos + 1, cc, mt);
      } else if (cc < 15) {
        #pragma unroll
        for (int mt = 0; mt < 4; ++mt) an[mt] = loadA(0, cc + 1, mt);
      } else {
        #pragma unroll
        for (int mt = 0; mt < 4; ++mt) an[mt] = ac[mt];
      }
      v8bf bfr[4];
      #pragma unroll
      for (int nt = 0; nt < 4; ++nt)
        bfr[nt] = readB(buf, rbB + ky * 66 + kx + nt * 16);
      #pragma unroll
      for (int mt = 0; mt < 4; ++mt)
        #pragma unroll
        for (int nt = 0; nt < 4; ++nt)
          acc[mt][nt] = __builtin_amdgcn_mfma_f32_16x16x32_bf16(ac[mt], bfr[nt], acc[mt][nt], 0, 0, 0);
      if (pos == 8) { __syncthreads(); buf ^= 1; }
      #pragma unroll
      for (int mt = 0; mt < 4; ++mt) ac[mt] = an[mt];
    }
  }

  // BN + ReLU
  float vals[4][4][4];
  #pragma unroll
  for (int mt = 0; mt < 4; ++mt) {
    const int ocb = ochalf * 64 + mt * 16 + ((lane >> 4) << 2);
    #pragma unroll
    for (int j = 0; j < 4; ++j) {
      const float s = scl[ocb + j], tt = bil[ocb + j];
      #pragma unroll
      for (int nt = 0; nt < 4; ++nt) vals[mt][nt][j] = fmaxf(fmaf(acc[mt][nt][j], s, tt), 0.f);
    }
  }

  if (octile == 2) {
    // emb2 (oc 256..383): NCHW f32 to d_out + y2 atomics + NHWC f32 to F2 (2 swizzled T rounds)
    #pragma unroll
    for (int mt = 0; mt < 4; ++mt)
      #pragma unroll
      for (int j = 0; j < 4; ++j) {
        const int ocl = ochalf * 64 + mt * 16 + ((lane >> 4) << 2) + j;
        float* orow = out2 + ((size_t)(n * 128 + ocl)) * 4096 + (h0 + prow) * 64;
        #pragma unroll
        for (int nt = 0; nt < 4; ++nt) orow[nt * 16 + (lane & 15)] = vals[mt][nt][j];
      }
    if (n < 2) {
      #pragma unroll
      for (int nt = 0; nt < 4; ++nt) {
        float s = 0.f;
        #pragma unroll
        for (int mt = 0; mt < 4; ++mt)
          #pragma unroll
          for (int j = 0; j < 4; ++j) s = fmaf(vals[mt][nt][j], vals[mt][nt][j], s);
        s += __shfl_xor(s, 16);
        s += __shfl_xor(s, 32);
        if ((lane >> 4) == 0)
          atomicAdd(&Y2[(size_t)(n * 68 + h0 + prow + 2) * 68 + nt * 16 + (lane & 15) + 2], s);
      }
    }
    float* T = (float*)lds;  // [128 px][64 oc] f32, 16-slot XOR swizzle
    #pragma unroll 1
    for (int mr = 0; mr < 2; ++mr) {
      __syncthreads();
      if (ochalf == mr) {
        #pragma unroll
        for (int mt = 0; mt < 4; ++mt)
          #pragma unroll
          for (int nt = 0; nt < 4; ++nt) {
            const int p = prow * 64 + nt * 16 + (lane & 15);
            #pragma unroll
            for (int j = 0; j < 4; ++j) {
              const int c = mt * 16 + ((lane >> 4) << 2) + j;
              T[p * 64 + (((c >> 2) ^ (p & 15)) << 2) + (c & 3)] = vals[mt][nt][j];
            }
          }
      }
      __syncthreads();
      const int p = tid >> 1, half = tid & 1;
      float* dst = F2 + ((size_t)((n * 68 + h0 + (p >> 6) + 2) * 68 + (p & 63) + 2)) * 128 + mr * 64 + half * 32;
      #pragma unroll
      for (int i = 0; i < 8; ++i) {
        const int s = (half * 8 + i) ^ (p & 15);
        *(float4*)(dst + i * 4) = *(const float4*)(T + p * 64 + s * 4);
      }
    }
  } else {
    // emb (oc 0..255): NHWC bf16 to Fs via swizzled T [128 px][128 oc] bf16
    u16* T = (u16*)lds;
    #pragma unroll
    for (int mt = 0; mt < 4; ++mt)
      #pragma unroll
      for (int nt = 0; nt < 4; ++nt) {
        const int p = prow * 64 + nt * 16 + (lane & 15);
        #pragma unroll
        for (int jj = 0; jj < 2; ++jj) {
          const u32 pk = (u32)f2bf(vals[mt][nt][2 * jj]) | ((u32)f2bf(vals[mt][nt][2 * jj + 1]) << 16);
          const int c = ochalf * 64 + mt * 16 + ((lane >> 4) << 2) + 2 * jj;
          *(u32*)(T + p * 128 + (((c >> 3) ^ (p & 15)) << 3) + (c & 7)) = pk;
        }
      }
    __syncthreads();
    const int p = tid >> 1, half = tid & 1;
    u16* dst = Fs + ((size_t)((n * 68 + h0 + (p >> 6) + 2) * 68 + (p & 63) + 2)) * 256 + octile * 128 + half * 64;
    #pragma unroll
    for (int i = 0; i < 8; ++i) {
      const int s = (half * 8 + i) ^ (p & 15);
      *(u16x8*)(dst + i * 8) = *(const u16x8*)(T + p * 128 + s * 8);
    }
  }
}

// ---------------- fused distance + softmax + warp -> fea (16 lanes/px, L2-direct) ----------------
__global__ __launch_bounds__(256) void k_dw(const float* __restrict__ F2, const float* __restrict__ Y2,
                                            const u16* __restrict__ Fs, u16* __restrict__ Fea) {
  const int t = blockIdx.x * 256 + threadIdx.x;
  const int g = t & 15;
  const int px = t >> 4;
  const int n = px >> 12;
  const int p = px & 4095;
  const int h = p >> 6, w = p & 63;

  // phase 1: distances over 8 channels (g*8) of F2, reduce over 16 lanes
  const float4* c2p = (const float4*)(F2 + ((size_t)(((n + 2) * 68 + h + 2) * 68 + (w + 2))) * 128 + g * 8);
  float4 c2v[2];
  float x2 = 0.f;
  #pragma unroll
  for (int i = 0; i < 2; ++i) {
    c2v[i] = c2p[i];
    x2 += c2v[i].x * c2v[i].x + c2v[i].y * c2v[i].y + c2v[i].z * c2v[i].z + c2v[i].w * c2v[i].w;
  }
  float cross[25];
  #pragma unroll
  for (int dy = 0; dy < 5; ++dy) {
    const float* rowp = F2 + ((size_t)((n * 68 + h + dy) * 68 + w)) * 128 + g * 8;
    #pragma unroll
    for (int dx = 0; dx < 5; ++dx) {
      const float4* wp = (const float4*)(rowp + dx * 128);
      float s = 0.f;
      #pragma unroll
      for (int i = 0; i < 2; ++i) {
        const float4 u = wp[i];
        s += c2v[i].x * u.x + c2v[i].y * u.y + c2v[i].z * u.z + c2v[i].w * u.w;
      }
      cross[dy * 5 + dx] = s;
    }
  }
  x2 += __shfl_xor(x2, 1); x2 += __shfl_xor(x2, 2); x2 += __shfl_xor(x2, 4); x2 += __shfl_xor(x2, 8);
  #pragma unroll
  for (int o = 0; o < 25; ++o) {
    cross[o] += __shfl_xor(cross[o], 1);
    cross[o] += __shfl_xor(cross[o], 2);
    cross[o] += __shfl_xor(cross[o], 4);
    cross[o] += __shfl_xor(cross[o], 8);
  }
  float wv[25], mx = -1e30f;
  #pragma unroll
  for (int dy = 0; dy < 5; ++dy)
    #pragma unroll
    for (int dx = 0; dx < 5; ++dx) {
      const int o = dy * 5 + dx;
      const float y2v = Y2[(size_t)(n * 68 + h + dy) * 68 + (w + dx)];
      const float dist = x2 + y2v - 2.f * cross[o];
      const float l = 1.f / (dist + 1e-5f);
      wv[o] = l;
      mx = fmaxf(mx, l);
    }
  float ssum = 0.f;
  #pragma unroll
  for (int o = 0; o < 25; ++o) { const float e = __expf(wv[o] - mx); wv[o] = e; ssum += e; }
  const float inv = 1.f / ssum;
  #pragma unroll
  for (int o = 0; o < 25; ++o) wv[o] *= inv;

  // phase 2: warp over 16 channels (g*16) of Fs
  float facc[16];
  #pragma unroll
  for (int i = 0; i < 16; ++i) facc[i] = 0.f;
  #pragma unroll
  for (int dy = 0; dy < 5; ++dy) {
    const u16* rp = Fs + ((size_t)((n * 68 + h + dy) * 68 + w)) * 256 + g * 16;
    #pragma unroll
    for (int dx = 0; dx < 5; ++dx) {
      const float wt = wv[dy * 5 + dx];
      const u16x8* up = (const u16x8*)(rp + dx * 256);
      #pragma unroll
      for (int k = 0; k < 2; ++k) {
        const u16x8 u = up[k];
        #pragma unroll
        for (int j = 0; j < 8; ++j) facc[k * 8 + j] = fmaf(wt, bf2f(u[j]), facc[k * 8 + j]);
      }
    }
  }
  const u16x8* cip = (const u16x8*)(Fs + ((size_t)(((n + 2) * 68 + h + 2) * 68 + (w + 2))) * 256 + g * 16);
  u16x8* dp = (u16x8*)(Fea + ((size_t)(n * 4096 + p)) * 256 + g * 16);
  #pragma unroll
  for (int k = 0; k < 2; ++k) {
    const u16x8 cu = cip[k];
    u16x8 ou;
    #pragma unroll
    for (int j = 0; j < 8; ++j)
      ou[j] = f2bf(0.5f * (bf2f(cu[j]) + facc[k * 8 + j] * (1.f / 25.f)));
    dp[k] = ou;
  }
}

// ---------------- logits (124x256 via MFMA) + log_softmax ----------------
__global__ __launch_bounds__(128) void k_logits(const u16* __restrict__ Fea, const u16* __restrict__ Wl,
                                                const float* __restrict__ lb, float* __restrict__ xout) {
  const int wvi = threadIdx.x >> 6, lane = threadIdx.x & 63;
  const int wid = blockIdx.x * 2 + wvi;
  const int n = wid >> 8;
  const int p0 = (wid & 255) * 16;
  const int lp = lane & 15;
  const int kb = (lane >> 4) * 8;

  v4f acc[8];
  #pragma unroll
  for (int mt = 0; mt < 8; ++mt) acc[mt] = (v4f){0.f, 0.f, 0.f, 0.f};

  #pragma unroll
  for (int kc = 0; kc < 8; ++kc) {
    const v8bf b = *(const v8bf*)(Fea + ((size_t)(n * 4096 + p0 + lp)) * 256 + kc * 32 + kb);
    #pragma unroll
    for (int mt = 0; mt < 8; ++mt) {
      const v8bf a = *(const v8bf*)(Wl + ((size_t)(mt * 16 + lp)) * 256 + kc * 32 + kb);
      acc[mt] = __builtin_amdgcn_mfma_f32_16x16x32_bf16(a, b, acc[mt], 0, 0, 0);
    }
  }
  const int r0 = (lane >> 4) * 4;
  float v[8][4];
  float mx = -1e30f;
  #pragma unroll
  for (int mt = 0; mt < 8; ++mt)
    #pragma unroll
    for (int j = 0; j < 4; ++j) {
      const int cls = mt * 16 + r0 + j;
      const float val = (cls < 124) ? (acc[mt][j] + lb[cls]) : -1e30f;
      v[mt][j] = val;
      mx = fmaxf(mx, val);
    }
  mx = fmaxf(mx, __shfl_xor(mx, 16));
  mx = fmaxf(mx, __shfl_xor(mx, 32));
  float s = 0.f;
  #pragma unroll
  for (int mt = 0; mt < 8; ++mt)
    #pragma unroll
    for (int j = 0; j < 4; ++j) {
      const int cls = mt * 16 + r0 + j;
      if (cls < 124) s += __expf(v[mt][j] - mx);
    }
  s += __shfl_xor(s, 16);
  s += __shfl_xor(s, 32);
  const float lz = mx + logf(s);
  #pragma unroll
  for (int mt = 0; mt < 8; ++mt)
    #pragma unroll
    for (int j = 0; j < 4; ++j) {
      const int cls = mt * 16 + r0 + j;
      if (cls < 124)
        xout[((size_t)(n * 124 + cls)) * 4096 + p0 + lp] = v[mt][j] - lz;
    }
}

extern "C" void kernel_launch(void* const* d_in, const int* in_sizes, int n_in,
                              void* d_out, int out_size, void* d_ws, size_t ws_size,
                              hipStream_t stream) {
  (void)in_sizes; (void)n_in; (void)out_size;
  const float* clip  = (const float*)d_in[0];
  const float* embW  = (const float*)d_in[2];
  const float* eg    = (const float*)d_in[3];
  const float* eb    = (const float*)d_in[4];
  const float* em    = (const float*)d_in[5];
  const float* ev    = (const float*)d_in[6];
  const float* emb2W = (const float*)d_in[7];
  const float* e2g   = (const float*)d_in[8];
  const float* e2b   = (const float*)d_in[9];
  const float* e2m   = (const float*)d_in[10];
  const float* e2v   = (const float*)d_in[11];
  const float* lw    = (const float*)d_in[12];
  const float* lb    = (const float*)d_in[13];

  char* ws = (char*)d_ws;
  u16*   Xh  = (u16*)(ws + XH_OFF);
  u16*   Wf  = (u16*)(ws + WT_OFF);
  u16*   Fs  = (u16*)(ws + FS_OFF);
  float* F2  = (float*)(ws + F2_OFF);
  float* Y2  = (float*)(ws + Y2_OFF);
  u16*   Fea = (u16*)(ws + FEA_OFF);
  u16*   Wl  = (u16*)(ws + WL_OFF);
  float* sc  = (float*)(ws + SC_OFF);
  float* bi  = sc + 384;

  float* xout = (float*)d_out;
  float* out2 = xout + (size_t)2 * 124 * 64 * 64;

  if (ws_size < WS_TOTAL) return;

  k_init<<<256, 256, 0, stream>>>(eg, eb, em, ev, e2g, e2b, e2m, e2v, lw, Xh, Fs, F2, Y2, Wl, sc, bi);
  k_prep_x<<<512, 256, 0, stream>>>(clip, Xh);
  k_prep_w<<<384, 256, 0, stream>>>(embW, emb2W, Wf);
  k_conv<<<384, 256, 0, stream>>>(Xh, Wf, sc, bi, out2, F2, Fs, Y2);
  k_dw<<<512, 256, 0, stream>>>(F2, Y2, Fs, Fea);
  k_logits<<<256, 128, 0, stream>>>(Fea, Wl, lb, xout);
}

// Round 4
// 217.624 us; speedup vs baseline: 1.0178x; 1.0178x over previous
//
#include <hip/hip_runtime.h>
#include <hip/hip_bf16.h>
#include <stdint.h>

// WarpNet: conv_bn_relu(512->384 combined) -> window-distance softmax warp -> 1x1 conv -> log_softmax

typedef float v4f __attribute__((ext_vector_type(4)));
typedef __bf16 v8bf __attribute__((ext_vector_type(8)));
typedef unsigned short u16;
typedef unsigned int u32;
typedef u16 u16x8 __attribute__((ext_vector_type(8)));

// ---------------- workspace layout (bytes) ----------------
constexpr size_t XH_OFF  = 0;                                  // padded NHWC input bf16 [4][66][66][512]
constexpr size_t XH_BYTES = (size_t)4*66*66*512*2;
constexpr size_t WT_OFF  = XH_OFF + XH_BYTES;                  // weight FRAGMENTS bf16 [9 pos][16 cc][24 ocb][64 lane][8]
constexpr size_t WT_BYTES = (size_t)9*16*24*64*8*2;
constexpr size_t FS_OFF  = WT_OFF + WT_BYTES;                  // clip_emb_s NHWC bf16 [4][68][68][256] (pad2)
constexpr size_t FS_BYTES = (size_t)4*68*68*256*2;
constexpr size_t F2_OFF  = FS_OFF + FS_BYTES;                  // clip_emb2 NHWC f32 [4][68][68][128] (pad2)
constexpr size_t F2_BYTES = (size_t)4*68*68*128*4;
constexpr size_t Y2_OFF  = F2_OFF + F2_BYTES;                  // y2 f32 [2][68][68] (border 1e20, interior atomics)
constexpr size_t Y2_BYTES = (size_t)2*68*68*4;
constexpr size_t FEA_OFF = Y2_OFF + Y2_BYTES;                  // final_fea bf16 [2][4096][256]
constexpr size_t FEA_BYTES = (size_t)2*4096*256*2;
constexpr size_t WL_OFF  = FEA_OFF + FEA_BYTES;                // last_W bf16 [128][256]
constexpr size_t WL_BYTES = (size_t)128*256*2;
constexpr size_t SC_OFF  = WL_OFF + WL_BYTES;                  // sc[384], bi[384] f32
constexpr size_t WS_TOTAL = SC_OFF + 768*4;

__device__ __forceinline__ float bf2f(u16 h) { return __uint_as_float(((u32)h) << 16); }
__device__ __forceinline__ u16 f2bf(float f) {
  u32 u = __float_as_uint(f);
  return (u16)((u + 0x7fffu + ((u >> 16) & 1u)) >> 16);
}

__device__ __forceinline__ void gld16(const void* g, const void* l) {
  __builtin_amdgcn_global_load_lds(
      (const __attribute__((address_space(1))) void*)(uintptr_t)g,
      (__attribute__((address_space(3))) void*)(u32)(uintptr_t)l,
      16, 0, 0);
}

// ---------------- init: borders, Y2, Wl, sc/bi (fused) ----------------
__global__ void k_init(const float* __restrict__ eg, const float* __restrict__ eb,
                       const float* __restrict__ em, const float* __restrict__ ev,
                       const float* __restrict__ e2g, const float* __restrict__ e2b,
                       const float* __restrict__ e2m, const float* __restrict__ e2v,
                       const float* __restrict__ lw,
                       u16* __restrict__ Xh, u16* __restrict__ Fs, float* __restrict__ F2,
                       float* __restrict__ Y2, u16* __restrict__ Wl,
                       float* __restrict__ sc, float* __restrict__ bi) {
  const u32 N0 = 4u * 260u * 64u;   // Xh border u16x8 chunks
  const u32 N1 = 4u * 528u * 32u;   // Fs border u16x8 chunks
  const u32 N2 = 4u * 528u * 32u;   // F2 border float4 chunks
  const u32 N3 = 2u * 68u * 68u;    // Y2 floats
  const u32 N4 = 4096u;             // Wl u16x8 chunks
  const u32 N5 = 384u;              // sc/bi
  const u32 TOT = N0 + N1 + N2 + N3 + N4 + N5;
  const u16x8 z8 = {0,0,0,0,0,0,0,0};
  for (u32 i = blockIdx.x * 256u + threadIdx.x; i < TOT; i += gridDim.x * 256u) {
    if (i < N0) {
      const u32 img = i / (260u * 64u);
      const u32 rem = i - img * (260u * 64u);
      const u32 r = rem >> 6, ch8 = rem & 63u;
      u32 prow, pcol;
      if (r < 132u) { prow = (r >= 66u) ? 65u : 0u; pcol = r - ((r >= 66u) ? 66u : 0u); }
      else { const u32 rr = r - 132u; prow = 1u + (rr >> 1); pcol = (rr & 1u) * 65u; }
      *(u16x8*)(Xh + ((size_t)((img * 66u + prow) * 66u + pcol)) * 512u + ch8 * 8u) = z8;
    } else if (i < N0 + N1 + N2) {
      const bool isF2 = (i >= N0 + N1);
      const u32 j = isF2 ? (i - N0 - N1) : (i - N0);
      const u32 img = j / (528u * 32u);
      const u32 rem = j - img * (528u * 32u);
      const u32 r = rem >> 5, cg = rem & 31u;
      u32 prow, pcol;
      if (r < 272u) { const u32 q = r / 68u; prow = (q < 2u) ? q : q + 64u; pcol = r - q * 68u; }
      else { const u32 rr = r - 272u; prow = 2u + (rr >> 2); const u32 c = rr & 3u; pcol = (c < 2u) ? c : c + 64u; }
      if (isF2) {
        const float4 zf = {0.f, 0.f, 0.f, 0.f};
        *(float4*)(F2 + ((size_t)((img * 68u + prow) * 68u + pcol)) * 128u + cg * 4u) = zf;
      } else {
        *(u16x8*)(Fs + ((size_t)((img * 68u + prow) * 68u + pcol)) * 256u + cg * 8u) = z8;
      }
    } else if (i < N0 + N1 + N2 + N3) {
      const u32 j = i - N0 - N1 - N2;
      const u32 n = j / 4624u, rc = j - n * 4624u;
      const u32 rr = rc / 68u, cc = rc - rr * 68u;
      const bool interior = (rr >= 2u && rr < 66u && cc >= 2u && cc < 66u);
      Y2[j] = interior ? 0.f : 1e20f;
    } else if (i < N0 + N1 + N2 + N3 + N4) {
      const u32 j = i - N0 - N1 - N2 - N3;
      const u32 row = j >> 5, c8 = (j & 31u) * 8u;
      u16x8 o;
      #pragma unroll
      for (int k = 0; k < 8; ++k) o[k] = (row < 124u) ? f2bf(lw[row * 256u + c8 + k]) : (u16)0;
      *(u16x8*)(Wl + (size_t)row * 256u + c8) = o;
    } else {
      const u32 id = i - N0 - N1 - N2 - N3 - N4;
      float g, b, m, v;
      if (id < 256u) { g = eg[id]; b = eb[id]; m = em[id]; v = ev[id]; }
      else { const u32 q = id - 256u; g = e2g[q]; b = e2b[q]; m = e2m[q]; v = e2v[q]; }
      const float s = g / sqrtf(v + 1e-5f);
      sc[id] = s;
      bi[id] = b - m * s;
    }
  }
}

// ---------------- NCHW f32 -> padded NHWC bf16 ----------------
__global__ __launch_bounds__(256) void k_prep_x(const float* __restrict__ X, u16* __restrict__ Xh) {
  __shared__ __align__(16) float tile[64 * 65];
  const int tid = threadIdx.x;
  const int n = blockIdx.x >> 7;
  const int rem = blockIdx.x & 127;
  const int h = rem >> 1, chalf = rem & 1;
  const int wq = tid >> 6, wcol = tid & 63;
  #pragma unroll 1
  for (int it = 0; it < 4; ++it) {
    const int c0 = chalf * 256 + it * 64;
    __syncthreads();
    #pragma unroll
    for (int i = 0; i < 16; ++i) {
      const int cl = i * 4 + wq;
      tile[cl * 65 + wcol] = X[((size_t)(n * 512 + c0 + cl)) * 4096 + h * 64 + wcol];
    }
    __syncthreads();
    const int w = tid >> 2, cg = tid & 3;
    u16x8 a, b;
    #pragma unroll
    for (int j = 0; j < 8; ++j) a[j] = f2bf(tile[(cg * 16 + j) * 65 + w]);
    #pragma unroll
    for (int j = 0; j < 8; ++j) b[j] = f2bf(tile[(cg * 16 + 8 + j) * 65 + w]);
    u16* dst = Xh + ((size_t)((n * 66 + h + 1) * 66 + (w + 1))) * 512 + c0 + cg * 16;
    *(u16x8*)dst = a;
    *((u16x8*)dst + 1) = b;
  }
}

// ---------------- weights [oc][512][3][3] f32 -> fragment layout [pos][cc][ocb][lane][8] bf16 ----------------
__global__ __launch_bounds__(256) void k_prep_w(const float* __restrict__ embW, const float* __restrict__ emb2W,
                                                u16* __restrict__ Wf) {
  __shared__ float row[4608];
  const int oc = blockIdx.x;
  const int tid = threadIdx.x;
  const float* src = (oc < 256) ? (embW + (size_t)oc * 4608) : (emb2W + (size_t)(oc - 256) * 4608);
  for (int i = tid; i < 4608; i += 256) row[i] = src[i];
  __syncthreads();
  const int cc = tid >> 4;             // ch = 2*tid: cc = ch>>5
  const int slot = (tid >> 2) & 3;     // (ch>>3)&3
  const int e = 2 * (tid & 3);         // ch&7
  const int r = oc & 15, ocb = oc >> 4;
  #pragma unroll
  for (int pos = 0; pos < 9; ++pos) {
    const u32 pk = (u32)f2bf(row[(2 * tid) * 9 + pos]) | ((u32)f2bf(row[(2 * tid + 1) * 9 + pos]) << 16);
    *(u32*)(Wf + ((size_t)((pos * 16 + cc) * 24 + ocb)) * 512 + (slot * 16 + r) * 8 + e) = pk;
  }
}

// ---------------- implicit-GEMM conv + BN + ReLU (+ y2 atomics) ----------------
// grid 512: octile(2:192oc) x n(4) x row(64). block = 192oc x 64px, 2 waves of 96oc x 64px (mt=6, nt=4).
// A staged fragment-verbatim via gld16 (conflict-free reads, no swizzle). B swizzled (round-3-validated).
// LDS: A 2x12288 [0,24576) | B 2x12672 [24576,49920) | sc/bi [49920,51456). Epilogue T overlays [0,40960).
__global__ __launch_bounds__(128) void k_conv(const u16* __restrict__ Xh, const u16* __restrict__ Wf,
                                              const float* __restrict__ sc, const float* __restrict__ bi,
                                              float* __restrict__ out2, float* __restrict__ F2,
                                              u16* __restrict__ Fs, float* __restrict__ Y2) {
  __shared__ __align__(16) char lds[51456];
  const int tid = threadIdx.x;
  const int wv = tid >> 6, lane = tid & 63;
  const int octile = blockIdx.x >> 8;
  const int rest = blockIdx.x & 255;
  const int n = rest >> 6, h = rest & 63;
  const int oc0b = octile * 12;

  float* scl = (float*)(lds + 49920);
  float* bil = scl + 192;
  for (int i = tid; i < 192; i += 128) {
    scl[i] = sc[octile * 192 + i];
    bil[i] = bi[octile * 192 + i];
  }

  // B staging sources: 198 cols (3 rows x 66) x 4 slots = 792 16B chunks, swizzled source slot
  const u16* xbase = Xh + (size_t)n * 66 * 66 * 512;
  int bofs[7];
  #pragma unroll
  for (int k = 0; k < 7; ++k) {
    const int idx = k * 128 + tid;
    if (idx < 792) {
      const int col = idx >> 2;
      const int ssrc = (idx & 3) ^ ((col >> 1) & 3);
      const int imgrow = col / 66, c = col - imgrow * 66;
      bofs[k] = ((h + imgrow) * 66 + c) * 512 + ssrc * 8;
    } else bofs[k] = 0;
  }

  auto stageA = [&](int pos, int cc, int buf) {
    const u16* base = Wf + ((size_t)((pos * 16 + cc) * 24 + oc0b)) * 512;
    #pragma unroll
    for (int k = 0; k < 6; ++k) {
      const int frag = 2 * k + wv;
      gld16(base + frag * 512 + lane * 8, lds + buf * 12288 + (frag * 64 + lane) * 16);
    }
  };
  auto stageB = [&](int cc, int buf) {
    char* base = lds + 24576 + buf * 12672;
    #pragma unroll
    for (int k = 0; k < 6; ++k)
      gld16(xbase + bofs[k] + cc * 32, base + (k * 128 + tid) * 16);
    if (tid < 24) gld16(xbase + bofs[6] + cc * 32, base + (768 + tid) * 16);
  };

  v4f acc[6][4];
  #pragma unroll
  for (int mt = 0; mt < 6; ++mt)
    #pragma unroll
    for (int nt = 0; nt < 4; ++nt) acc[mt][nt] = (v4f){0.f, 0.f, 0.f, 0.f};

  int bA = 0, bB = 0;
  stageB(0, 0);
  stageA(0, 0, 0);
  __syncthreads();

  const int r0 = lane & 15;
  const int slotb = lane >> 4;
  const char* ldsB = lds + 24576;

  #pragma unroll 1
  for (int cc = 0; cc < 16; ++cc) {
    #pragma unroll
    for (int pos = 0; pos < 9; ++pos) {
      const int ky = pos / 3, kx = pos % 3;
      if (pos == 5 && cc < 15) stageB(cc + 1, bB ^ 1);
      if (pos < 8) stageA(pos + 1, cc, bA ^ 1);
      else if (cc < 15) stageA(0, cc + 1, bA ^ 1);
      v8bf af[6], bf4[4];
      const char* pA = lds + bA * 12288 + wv * 6144 + lane * 16;
      #pragma unroll
      for (int mt = 0; mt < 6; ++mt) af[mt] = *(const v8bf*)(pA + mt * 1024);
      #pragma unroll
      for (int nt = 0; nt < 4; ++nt) {
        const int rb = ky * 66 + kx + nt * 16 + r0;
        bf4[nt] = *(const v8bf*)(ldsB + bB * 12672 + rb * 64 + ((slotb ^ ((rb >> 1) & 3)) << 4));
      }
      #pragma unroll
      for (int mt = 0; mt < 6; ++mt)
        #pragma unroll
        for (int nt = 0; nt < 4; ++nt)
          acc[mt][nt] = __builtin_amdgcn_mfma_f32_16x16x32_bf16(af[mt], bf4[nt], acc[mt][nt], 0, 0, 0);
      __syncthreads();
      bA ^= 1;
      if (pos == 8) bB ^= 1;
    }
  }

  // BN + ReLU
  const int q4 = (lane >> 4) << 2;
  float vals[6][4][4];
  #pragma unroll
  for (int mt = 0; mt < 6; ++mt) {
    const int ocb = wv * 96 + mt * 16 + q4;
    #pragma unroll
    for (int j = 0; j < 4; ++j) {
      const float s = scl[ocb + j], tt = bil[ocb + j];
      #pragma unroll
      for (int nt = 0; nt < 4; ++nt) vals[mt][nt][j] = fmaxf(fmaf(acc[mt][nt][j], s, tt), 0.f);
    }
  }

  if (octile == 0) {
    // all 192 oc -> Fs ch 0..191 via swizzled T [64 px][256 u16]
    u16* T = (u16*)lds;
    #pragma unroll
    for (int mt = 0; mt < 6; ++mt)
      #pragma unroll
      for (int nt = 0; nt < 4; ++nt) {
        const int p = nt * 16 + r0;
        #pragma unroll
        for (int jj = 0; jj < 2; ++jj) {
          const u32 pk = (u32)f2bf(vals[mt][nt][2 * jj]) | ((u32)f2bf(vals[mt][nt][2 * jj + 1]) << 16);
          const int c = wv * 96 + mt * 16 + q4 + 2 * jj;
          *(u32*)(T + p * 256 + (((c >> 3) ^ (p & 15)) << 3) + (c & 7)) = pk;
        }
      }
    __syncthreads();
    const int p = tid >> 1, half = tid & 1;
    u16* dst = Fs + ((size_t)((n * 68 + h + 2) * 68 + p + 2)) * 256 + half * 96;
    #pragma unroll
    for (int i = 0; i < 12; ++i) {
      const int cs = half * 12 + i;
      *(u16x8*)(dst + i * 8) = *(const u16x8*)(T + p * 256 + ((cs ^ (p & 15)) << 3));
    }
  } else {
    // oc 192..255 -> Fs ch 192..255 (T2); oc 256..383 -> out2 NCHW + y2 + F2 via T (f32)
    float* T = (float*)lds;            // [64 px][128 ch] f32 = 32KB
    u16* T2 = (u16*)(lds + 32768);     // [64 px][64 ch] u16 = 8KB
    #pragma unroll
    for (int mt = 0; mt < 6; ++mt) {
      const int fb = 192 + wv * 96 + mt * 16;
      if (fb >= 256) {
        // emb2
        #pragma unroll
        for (int j = 0; j < 4; ++j) {
          float* orow = out2 + ((size_t)(n * 128 + fb - 256 + q4 + j)) * 4096 + h * 64;
          #pragma unroll
          for (int nt = 0; nt < 4; ++nt) orow[nt * 16 + r0] = vals[mt][nt][j];
        }
        if (n < 2) {
          #pragma unroll
          for (int nt = 0; nt < 4; ++nt) {
            float s = 0.f;
            #pragma unroll
            for (int j = 0; j < 4; ++j) s = fmaf(vals[mt][nt][j], vals[mt][nt][j], s);
            s += __shfl_xor(s, 16);
            s += __shfl_xor(s, 32);
            if ((lane >> 4) == 0)
              atomicAdd(&Y2[(size_t)(n * 68 + h + 2) * 68 + nt * 16 + r0 + 2], s);
          }
        }
        #pragma unroll
        for (int nt = 0; nt < 4; ++nt) {
          const int p = nt * 16 + r0;
          #pragma unroll
          for (int j = 0; j < 4; ++j) {
            const int c = fb - 256 + q4 + j;
            T[p * 128 + (((c >> 2) ^ (p & 15)) << 2) + (c & 3)] = vals[mt][nt][j];
          }
        }
      } else {
        // emb (wv==0, mt<4): Fs ch 192 + mt*16 ...
        #pragma unroll
        for (int nt = 0; nt < 4; ++nt) {
          const int p = nt * 16 + r0;
          #pragma unroll
          for (int jj = 0; jj < 2; ++jj) {
            const u32 pk = (u32)f2bf(vals[mt][nt][2 * jj]) | ((u32)f2bf(vals[mt][nt][2 * jj + 1]) << 16);
            const int c = mt * 16 + q4 + 2 * jj;   // 0..63
            *(u32*)(T2 + p * 64 + (((c >> 3) ^ (p & 7)) << 3) + (c & 7)) = pk;
          }
        }
      }
    }
    __syncthreads();
    const int p = tid >> 1, half = tid & 1;
    float* f2dst = F2 + ((size_t)((n * 68 + h + 2) * 68 + p + 2)) * 128 + half * 64;
    #pragma unroll
    for (int i = 0; i < 16; ++i) {
      const int cs = half * 16 + i;
      *(float4*)(f2dst + i * 4) = *(const float4*)(T + p * 128 + ((cs ^ (p & 15)) << 2));
    }
    u16* fsdst = Fs + ((size_t)((n * 68 + h + 2) * 68 + p + 2)) * 256 + 192 + half * 32;
    #pragma unroll
    for (int i = 0; i < 4; ++i) {
      const int cs = half * 4 + i;
      *(u16x8*)(fsdst + i * 8) = *(const u16x8*)(T2 + p * 64 + ((cs ^ (p & 7)) << 3));
    }
  }
}

// ---------------- fused distance + softmax + warp -> fea (16 lanes/px, L2-direct) ----------------
__global__ __launch_bounds__(256) void k_dw(const float* __restrict__ F2, const float* __restrict__ Y2,
                                            const u16* __restrict__ Fs, u16* __restrict__ Fea) {
  const int t = blockIdx.x * 256 + threadIdx.x;
  const int g = t & 15;
  const int px = t >> 4;
  const int n = px >> 12;
  const int p = px & 4095;
  const int h = p >> 6, w = p & 63;

  // phase 1: distances over 8 channels (g*8) of F2, reduce over 16 lanes
  const float4* c2p = (const float4*)(F2 + ((size_t)(((n + 2) * 68 + h + 2) * 68 + (w + 2))) * 128 + g * 8);
  float4 c2v[2];
  float x2 = 0.f;
  #pragma unroll
  for (int i = 0; i < 2; ++i) {
    c2v[i] = c2p[i];
    x2 += c2v[i].x * c2v[i].x + c2v[i].y * c2v[i].y + c2v[i].z * c2v[i].z + c2v[i].w * c2v[i].w;
  }
  float cross[25];
  #pragma unroll
  for (int dy = 0; dy < 5; ++dy) {
    const float* rowp = F2 + ((size_t)((n * 68 + h + dy) * 68 + w)) * 128 + g * 8;
    #pragma unroll
    for (int dx = 0; dx < 5; ++dx) {
      const float4* wp = (const float4*)(rowp + dx * 128);
      float s = 0.f;
      #pragma unroll
      for (int i = 0; i < 2; ++i) {
        const float4 u = wp[i];
        s += c2v[i].x * u.x + c2v[i].y * u.y + c2v[i].z * u.z + c2v[i].w * u.w;
      }
      cross[dy * 5 + dx] = s;
    }
  }
  x2 += __shfl_xor(x2, 1); x2 += __shfl_xor(x2, 2); x2 += __shfl_xor(x2, 4); x2 += __shfl_xor(x2, 8);
  #pragma unroll
  for (int o = 0; o < 25; ++o) {
    cross[o] += __shfl_xor(cross[o], 1);
    cross[o] += __shfl_xor(cross[o], 2);
    cross[o] += __shfl_xor(cross[o], 4);
    cross[o] += __shfl_xor(cross[o], 8);
  }
  float wv[25], mx = -1e30f;
  #pragma unroll
  for (int dy = 0; dy < 5; ++dy)
    #pragma unroll
    for (int dx = 0; dx < 5; ++dx) {
      const int o = dy * 5 + dx;
      const float y2v = Y2[(size_t)(n * 68 + h + dy) * 68 + (w + dx)];
      const float dist = x2 + y2v - 2.f * cross[o];
      const float l = 1.f / (dist + 1e-5f);
      wv[o] = l;
      mx = fmaxf(mx, l);
    }
  float ssum = 0.f;
  #pragma unroll
  for (int o = 0; o < 25; ++o) { const float e = __expf(wv[o] - mx); wv[o] = e; ssum += e; }
  const float inv = 1.f / ssum;
  #pragma unroll
  for (int o = 0; o < 25; ++o) wv[o] *= inv;

  // phase 2: warp over 16 channels (g*16) of Fs
  float facc[16];
  #pragma unroll
  for (int i = 0; i < 16; ++i) facc[i] = 0.f;
  #pragma unroll
  for (int dy = 0; dy < 5; ++dy) {
    const u16* rp = Fs + ((size_t)((n * 68 + h + dy) * 68 + w)) * 256 + g * 16;
    #pragma unroll
    for (int dx = 0; dx < 5; ++dx) {
      const float wt = wv[dy * 5 + dx];
      const u16x8* up = (const u16x8*)(rp + dx * 256);
      #pragma unroll
      for (int k = 0; k < 2; ++k) {
        const u16x8 u = up[k];
        #pragma unroll
        for (int j = 0; j < 8; ++j) facc[k * 8 + j] = fmaf(wt, bf2f(u[j]), facc[k * 8 + j]);
      }
    }
  }
  const u16x8* cip = (const u16x8*)(Fs + ((size_t)(((n + 2) * 68 + h + 2) * 68 + (w + 2))) * 256 + g * 16);
  u16x8* dp = (u16x8*)(Fea + ((size_t)(n * 4096 + p)) * 256 + g * 16);
  #pragma unroll
  for (int k = 0; k < 2; ++k) {
    const u16x8 cu = cip[k];
    u16x8 ou;
    #pragma unroll
    for (int j = 0; j < 8; ++j)
      ou[j] = f2bf(0.5f * (bf2f(cu[j]) + facc[k * 8 + j] * (1.f / 25.f)));
    dp[k] = ou;
  }
}

// ---------------- logits (124x256 via MFMA) + log_softmax ----------------
__global__ __launch_bounds__(128) void k_logits(const u16* __restrict__ Fea, const u16* __restrict__ Wl,
                                                const float* __restrict__ lb, float* __restrict__ xout) {
  const int wvi = threadIdx.x >> 6, lane = threadIdx.x & 63;
  const int wid = blockIdx.x * 2 + wvi;
  const int n = wid >> 8;
  const int p0 = (wid & 255) * 16;
  const int lp = lane & 15;
  const int kb = (lane >> 4) * 8;

  v4f acc[8];
  #pragma unroll
  for (int mt = 0; mt < 8; ++mt) acc[mt] = (v4f){0.f, 0.f, 0.f, 0.f};

  #pragma unroll
  for (int kc = 0; kc < 8; ++kc) {
    const v8bf b = *(const v8bf*)(Fea + ((size_t)(n * 4096 + p0 + lp)) * 256 + kc * 32 + kb);
    #pragma unroll
    for (int mt = 0; mt < 8; ++mt) {
      const v8bf a = *(const v8bf*)(Wl + ((size_t)(mt * 16 + lp)) * 256 + kc * 32 + kb);
      acc[mt] = __builtin_amdgcn_mfma_f32_16x16x32_bf16(a, b, acc[mt], 0, 0, 0);
    }
  }
  const int r0 = (lane >> 4) * 4;
  float v[8][4];
  float mx = -1e30f;
  #pragma unroll
  for (int mt = 0; mt < 8; ++mt)
    #pragma unroll
    for (int j = 0; j < 4; ++j) {
      const int cls = mt * 16 + r0 + j;
      const float val = (cls < 124) ? (acc[mt][j] + lb[cls]) : -1e30f;
      v[mt][j] = val;
      mx = fmaxf(mx, val);
    }
  mx = fmaxf(mx, __shfl_xor(mx, 16));
  mx = fmaxf(mx, __shfl_xor(mx, 32));
  float s = 0.f;
  #pragma unroll
  for (int mt = 0; mt < 8; ++mt)
    #pragma unroll
    for (int j = 0; j < 4; ++j) {
      const int cls = mt * 16 + r0 + j;
      if (cls < 124) s += __expf(v[mt][j] - mx);
    }
  s += __shfl_xor(s, 16);
  s += __shfl_xor(s, 32);
  const float lz = mx + logf(s);
  #pragma unroll
  for (int mt = 0; mt < 8; ++mt)
    #pragma unroll
    for (int j = 0; j < 4; ++j) {
      const int cls = mt * 16 + r0 + j;
      if (cls < 124)
        xout[((size_t)(n * 124 + cls)) * 4096 + p0 + lp] = v[mt][j] - lz;
    }
}

extern "C" void kernel_launch(void* const* d_in, const int* in_sizes, int n_in,
                              void* d_out, int out_size, void* d_ws, size_t ws_size,
                              hipStream_t stream) {
  (void)in_sizes; (void)n_in; (void)out_size;
  const float* clip  = (const float*)d_in[0];
  const float* embW  = (const float*)d_in[2];
  const float* eg    = (const float*)d_in[3];
  const float* eb    = (const float*)d_in[4];
  const float* em    = (const float*)d_in[5];
  const float* ev    = (const float*)d_in[6];
  const float* emb2W = (const float*)d_in[7];
  const float* e2g   = (const float*)d_in[8];
  const float* e2b   = (const float*)d_in[9];
  const float* e2m   = (const float*)d_in[10];
  const float* e2v   = (const float*)d_in[11];
  const float* lw    = (const float*)d_in[12];
  const float* lb    = (const float*)d_in[13];

  char* ws = (char*)d_ws;
  u16*   Xh  = (u16*)(ws + XH_OFF);
  u16*   Wf  = (u16*)(ws + WT_OFF);
  u16*   Fs  = (u16*)(ws + FS_OFF);
  float* F2  = (float*)(ws + F2_OFF);
  float* Y2  = (float*)(ws + Y2_OFF);
  u16*   Fea = (u16*)(ws + FEA_OFF);
  u16*   Wl  = (u16*)(ws + WL_OFF);
  float* sc  = (float*)(ws + SC_OFF);
  float* bi  = sc + 384;

  float* xout = (float*)d_out;
  float* out2 = xout + (size_t)2 * 124 * 64 * 64;

  if (ws_size < WS_TOTAL) return;

  k_init<<<256, 256, 0, stream>>>(eg, eb, em, ev, e2g, e2b, e2m, e2v, lw, Xh, Fs, F2, Y2, Wl, sc, bi);
  k_prep_x<<<512, 256, 0, stream>>>(clip, Xh);
  k_prep_w<<<384, 256, 0, stream>>>(embW, emb2W, Wf);
  k_conv<<<512, 128, 0, stream>>>(Xh, Wf, sc, bi, out2, F2, Fs, Y2);
  k_dw<<<512, 256, 0, stream>>>(F2, Y2, Fs, Fea);
  k_logits<<<256, 128, 0, stream>>>(Fea, Wl, lb, xout);
}

// Round 6
// 192.490 us; speedup vs baseline: 1.1507x; 1.1306x over previous
//
#include <hip/hip_runtime.h>
#include <hip/hip_bf16.h>
#include <stdint.h>

// WarpNet: conv_bn_relu(512->384 combined) -> window-distance softmax warp -> 1x1 conv -> log_softmax

typedef float v4f __attribute__((ext_vector_type(4)));
typedef __bf16 v8bf __attribute__((ext_vector_type(8)));
typedef unsigned short u16;
typedef unsigned int u32;
typedef u16 u16x8 __attribute__((ext_vector_type(8)));

// ---------------- workspace layout (bytes) ----------------
constexpr size_t XH_OFF  = 0;                                  // padded NHWC input bf16 [4][66][66][512]
constexpr size_t XH_BYTES = (size_t)4*66*66*512*2;
constexpr size_t WT_OFF  = XH_OFF + XH_BYTES;                  // weight FRAGMENTS bf16 [9 pos][16 cc][24 ocb][64 lane][8]
constexpr size_t WT_BYTES = (size_t)9*16*24*64*8*2;
constexpr size_t FS_OFF  = WT_OFF + WT_BYTES;                  // clip_emb_s NHWC bf16 [4][68][68][256] (pad2)
constexpr size_t FS_BYTES = (size_t)4*68*68*256*2;
constexpr size_t F2_OFF  = FS_OFF + FS_BYTES;                  // clip_emb2 NHWC f32 [4][68][68][128] (pad2)
constexpr size_t F2_BYTES = (size_t)4*68*68*128*4;
constexpr size_t Y2_OFF  = F2_OFF + F2_BYTES;                  // y2 f32 [2][68][68] (border 1e20, interior atomics)
constexpr size_t Y2_BYTES = (size_t)2*68*68*4;
constexpr size_t FEA_OFF = Y2_OFF + Y2_BYTES;                  // final_fea bf16 [2][4096][256]
constexpr size_t FEA_BYTES = (size_t)2*4096*256*2;
constexpr size_t WL_OFF  = FEA_OFF + FEA_BYTES;                // last_W bf16 [128][256]
constexpr size_t WL_BYTES = (size_t)128*256*2;
constexpr size_t SC_OFF  = WL_OFF + WL_BYTES;                  // sc[384], bi[384] f32
constexpr size_t WS_TOTAL = SC_OFF + 768*4;

__device__ __forceinline__ float bf2f(u16 h) { return __uint_as_float(((u32)h) << 16); }
__device__ __forceinline__ u16 f2bf(float f) {
  u32 u = __float_as_uint(f);
  return (u16)((u + 0x7fffu + ((u >> 16) & 1u)) >> 16);
}

__device__ __forceinline__ void gld16(const void* g, const void* l) {
  __builtin_amdgcn_global_load_lds(
      (const __attribute__((address_space(1))) void*)(uintptr_t)g,
      (__attribute__((address_space(3))) void*)(u32)(uintptr_t)l,
      16, 0, 0);
}

// ---------------- merged prep: [0,256) init | [256,768) NCHW->NHWC | [768,1152) weights ----------------
__global__ __launch_bounds__(256) void k_prep(const float* __restrict__ X,
                       const float* __restrict__ embW, const float* __restrict__ emb2W,
                       const float* __restrict__ eg, const float* __restrict__ eb,
                       const float* __restrict__ em, const float* __restrict__ ev,
                       const float* __restrict__ e2g, const float* __restrict__ e2b,
                       const float* __restrict__ e2m, const float* __restrict__ e2v,
                       const float* __restrict__ lw,
                       u16* __restrict__ Xh, u16* __restrict__ Wf,
                       u16* __restrict__ Fs, float* __restrict__ F2,
                       float* __restrict__ Y2, u16* __restrict__ Wl,
                       float* __restrict__ sc, float* __restrict__ bi) {
  __shared__ __align__(16) char shbuf[18688];
  const int bid = blockIdx.x;
  const int tid = threadIdx.x;
  if (bid < 256) {
    // ---- init: borders, Y2, Wl, sc/bi ----
    const u32 N0 = 4u * 260u * 64u;
    const u32 N1 = 4u * 528u * 32u;
    const u32 N2 = 4u * 528u * 32u;
    const u32 N3 = 2u * 68u * 68u;
    const u32 N4 = 4096u;
    const u32 N5 = 384u;
    const u32 TOT = N0 + N1 + N2 + N3 + N4 + N5;
    const u16x8 z8 = {0,0,0,0,0,0,0,0};
    for (u32 i = bid * 256u + tid; i < TOT; i += 65536u) {
      if (i < N0) {
        const u32 img = i / (260u * 64u);
        const u32 rem = i - img * (260u * 64u);
        const u32 r = rem >> 6, ch8 = rem & 63u;
        u32 prow, pcol;
        if (r < 132u) { prow = (r >= 66u) ? 65u : 0u; pcol = r - ((r >= 66u) ? 66u : 0u); }
        else { const u32 rr = r - 132u; prow = 1u + (rr >> 1); pcol = (rr & 1u) * 65u; }
        *(u16x8*)(Xh + ((size_t)((img * 66u + prow) * 66u + pcol)) * 512u + ch8 * 8u) = z8;
      } else if (i < N0 + N1 + N2) {
        const bool isF2 = (i >= N0 + N1);
        const u32 j = isF2 ? (i - N0 - N1) : (i - N0);
        const u32 img = j / (528u * 32u);
        const u32 rem = j - img * (528u * 32u);
        const u32 r = rem >> 5, cg = rem & 31u;
        u32 prow, pcol;
        if (r < 272u) { const u32 q = r / 68u; prow = (q < 2u) ? q : q + 64u; pcol = r - q * 68u; }
        else { const u32 rr = r - 272u; prow = 2u + (rr >> 2); const u32 c = rr & 3u; pcol = (c < 2u) ? c : c + 64u; }
        if (isF2) {
          const float4 zf = {0.f, 0.f, 0.f, 0.f};
          *(float4*)(F2 + ((size_t)((img * 68u + prow) * 68u + pcol)) * 128u + cg * 4u) = zf;
        } else {
          *(u16x8*)(Fs + ((size_t)((img * 68u + prow) * 68u + pcol)) * 256u + cg * 8u) = z8;
        }
      } else if (i < N0 + N1 + N2 + N3) {
        const u32 j = i - N0 - N1 - N2;
        const u32 n = j / 4624u, rc = j - n * 4624u;
        const u32 rr = rc / 68u, cc = rc - rr * 68u;
        const bool interior = (rr >= 2u && rr < 66u && cc >= 2u && cc < 66u);
        Y2[j] = interior ? 0.f : 1e20f;
      } else if (i < N0 + N1 + N2 + N3 + N4) {
        const u32 j = i - N0 - N1 - N2 - N3;
        const u32 row = j >> 5, c8 = (j & 31u) * 8u;
        u16x8 o;
        #pragma unroll
        for (int k = 0; k < 8; ++k) o[k] = (row < 124u) ? f2bf(lw[row * 256u + c8 + k]) : (u16)0;
        *(u16x8*)(Wl + (size_t)row * 256u + c8) = o;
      } else {
        const u32 id = i - N0 - N1 - N2 - N3 - N4;
        float g, b, m, v;
        if (id < 256u) { g = eg[id]; b = eb[id]; m = em[id]; v = ev[id]; }
        else { const u32 q = id - 256u; g = e2g[q]; b = e2b[q]; m = e2m[q]; v = e2v[q]; }
        const float s = g / sqrtf(v + 1e-5f);
        sc[id] = s;
        bi[id] = b - m * s;
      }
    }
  } else if (bid < 768) {
    // ---- NCHW f32 -> padded NHWC bf16 ----
    float* tile = (float*)shbuf;  // [64][65]
    const int b2 = bid - 256;
    const int n = b2 >> 7;
    const int rem = b2 & 127;
    const int h = rem >> 1, chalf = rem & 1;
    const int wq = tid >> 6, wcol = tid & 63;
    #pragma unroll 1
    for (int it = 0; it < 4; ++it) {
      const int c0 = chalf * 256 + it * 64;
      __syncthreads();
      #pragma unroll
      for (int i = 0; i < 16; ++i) {
        const int cl = i * 4 + wq;
        tile[cl * 65 + wcol] = X[((size_t)(n * 512 + c0 + cl)) * 4096 + h * 64 + wcol];
      }
      __syncthreads();
      const int w = tid >> 2, cg = tid & 3;
      u16x8 a, b;
      #pragma unroll
      for (int j = 0; j < 8; ++j) a[j] = f2bf(tile[(cg * 16 + j) * 65 + w]);
      #pragma unroll
      for (int j = 0; j < 8; ++j) b[j] = f2bf(tile[(cg * 16 + 8 + j) * 65 + w]);
      u16* dst = Xh + ((size_t)((n * 66 + h + 1) * 66 + (w + 1))) * 512 + c0 + cg * 16;
      *(u16x8*)dst = a;
      *((u16x8*)dst + 1) = b;
    }
  } else {
    // ---- weights [oc][512][3][3] f32 -> fragment layout [pos][cc][ocb][lane][8] bf16 ----
    float* row = (float*)shbuf;  // [4608]
    const int oc = bid - 768;
    const float* src = (oc < 256) ? (embW + (size_t)oc * 4608) : (emb2W + (size_t)(oc - 256) * 4608);
    for (int i = tid; i < 4608; i += 256) row[i] = src[i];
    __syncthreads();
    const int cc = tid >> 4;
    const int slot = (tid >> 2) & 3;
    const int e = 2 * (tid & 3);
    const int r = oc & 15, ocb = oc >> 4;
    #pragma unroll
    for (int pos = 0; pos < 9; ++pos) {
      const u32 pk = (u32)f2bf(row[(2 * tid) * 9 + pos]) | ((u32)f2bf(row[(2 * tid + 1) * 9 + pos]) << 16);
      *(u32*)(Wf + ((size_t)((pos * 16 + cc) * 24 + ocb)) * 512 + (slot * 16 + r) * 8 + e) = pk;
    }
  }
}

// ---------------- implicit-GEMM conv + BN + ReLU (+ y2 atomics) ----------------
// grid 768: octile(6:64oc) x n(4) x pixtile(32:2rows). block = 64oc x 128px, 4 waves of 64oc x 32px.
// A staged fragment-verbatim (one gld16 per (pos,cc), linear conflict-free reads).
// B swizzled slot^((col>>1)&3) (validated r3/r4). 3 blocks/CU -> 12 waves/CU.
// LDS: A 2x4096 [0,8192) | B 2x16896 [8192,41984) | sc/bi [41984,42496). Epilogue T overlays [0,32768).
__global__ __launch_bounds__(256) void k_conv(const u16* __restrict__ Xh, const u16* __restrict__ Wf,
                                              const float* __restrict__ sc, const float* __restrict__ bi,
                                              float* __restrict__ out2, float* __restrict__ F2,
                                              u16* __restrict__ Fs, float* __restrict__ Y2) {
  __shared__ __align__(16) char lds[42496];
  const int tid = threadIdx.x;
  const int wv = tid >> 6, lane = tid & 63;
  const int octile = blockIdx.x >> 7;
  const int rest = blockIdx.x & 127;
  const int n = rest >> 5, pt = rest & 31;
  const int h0 = pt * 2;
  const int ocb0 = octile * 4;
  const int pxrow = wv >> 1;          // output row within the 2-row tile
  const int pxc0 = (wv & 1) * 32;     // col base of this wave's 32 px

  float* scl = (float*)(lds + 41984);
  float* bil = scl + 64;
  if (tid < 64) { scl[tid] = sc[octile * 64 + tid]; bil[tid] = bi[octile * 64 + tid]; }

  // B staging sources: 264 cols (4 rows x 66) x 4 slots = 1056 chunks, swizzled source slot
  const u16* xbase = Xh + (size_t)n * 66 * 66 * 512;
  int bofs[5];
  #pragma unroll
  for (int k = 0; k < 5; ++k) {
    const int idx = k * 256 + tid;
    if (idx < 1056) {
      const int col = idx >> 2;
      const int ssrc = (idx & 3) ^ ((col >> 1) & 3);
      const int imgrow = col / 66, c = col - imgrow * 66;
      bofs[k] = ((h0 + imgrow) * 66 + c) * 512 + ssrc * 8;
    } else bofs[k] = 0;
  }

  auto stageA = [&](int pos, int cc, int buf) {
    gld16(Wf + ((size_t)((pos * 16 + cc) * 24 + ocb0)) * 512 + tid * 8, lds + buf * 4096 + tid * 16);
  };
  auto stageB = [&](int cc, int buf) {
    char* base = lds + 8192 + buf * 16896;
    #pragma unroll
    for (int k = 0; k < 4; ++k)
      gld16(xbase + bofs[k] + cc * 32, base + k * 4096 + tid * 16);
    if (tid < 32) gld16(xbase + bofs[4] + cc * 32, base + 16384 + tid * 16);
  };

  v4f acc[4][2];
  #pragma unroll
  for (int mt = 0; mt < 4; ++mt) { acc[mt][0] = (v4f){0,0,0,0}; acc[mt][1] = (v4f){0,0,0,0}; }

  int bA = 0, bB = 0;
  stageB(0, 0);
  stageA(0, 0, 0);
  __syncthreads();

  const int r0 = lane & 15;
  const int slotb = lane >> 4;
  const char* ldsB = lds + 8192;

  #pragma unroll 1
  for (int cc = 0; cc < 16; ++cc) {
    #pragma unroll
    for (int pos = 0; pos < 9; ++pos) {
      const int ky = pos / 3, kx = pos % 3;
      if (pos < 8) {
        stageA(pos + 1, cc, bA ^ 1);
      } else if (cc < 15) {
        stageB(cc + 1, bB ^ 1);
        stageA(0, cc + 1, bA ^ 1);
      }
      v8bf af[4], bfr[2];
      const char* pA = lds + bA * 4096 + lane * 16;
      #pragma unroll
      for (int mt = 0; mt < 4; ++mt) af[mt] = *(const v8bf*)(pA + mt * 1024);
      #pragma unroll
      for (int nt = 0; nt < 2; ++nt) {
        const int rb = (pxrow + ky) * 66 + pxc0 + nt * 16 + r0 + kx;
        bfr[nt] = *(const v8bf*)(ldsB + bB * 16896 + rb * 64 + ((slotb ^ ((rb >> 1) & 3)) << 4));
      }
      #pragma unroll
      for (int mt = 0; mt < 4; ++mt)
        #pragma unroll
        for (int nt = 0; nt < 2; ++nt)
          acc[mt][nt] = __builtin_amdgcn_mfma_f32_16x16x32_bf16(af[mt], bfr[nt], acc[mt][nt], 0, 0, 0);
      __syncthreads();
      bA ^= 1;
      if (pos == 8) bB ^= 1;
    }
  }

  // BN + ReLU
  const int q4 = (lane >> 4) << 2;
  float vals[4][2][4];
  #pragma unroll
  for (int mt = 0; mt < 4; ++mt) {
    const int ocb = mt * 16 + q4;
    #pragma unroll
    for (int j = 0; j < 4; ++j) {
      const float s = scl[ocb + j], tt = bil[ocb + j];
      #pragma unroll
      for (int nt = 0; nt < 2; ++nt) vals[mt][nt][j] = fmaxf(fmaf(acc[mt][nt][j], s, tt), 0.f);
    }
  }

  if (octile < 4) {
    // emb (oc 0..255): NHWC bf16 to Fs via swizzled T [128 px][64 ch] u16
    u16* T = (u16*)lds;
    #pragma unroll
    for (int mt = 0; mt < 4; ++mt)
      #pragma unroll
      for (int nt = 0; nt < 2; ++nt) {
        const int p = pxrow * 64 + pxc0 + nt * 16 + r0;
        #pragma unroll
        for (int jj = 0; jj < 2; ++jj) {
          const int c = mt * 16 + q4 + 2 * jj;
          *(u32*)(T + p * 64 + (((c >> 3) ^ (p & 7)) << 3) + (c & 7)) =
              (u32)f2bf(vals[mt][nt][2 * jj]) | ((u32)f2bf(vals[mt][nt][2 * jj + 1]) << 16);
        }
      }
    __syncthreads();
    const int p = tid >> 1, half = tid & 1;
    u16* dst = Fs + ((size_t)((n * 68 + h0 + (p >> 6) + 2) * 68 + (p & 63) + 2)) * 256 + octile * 64 + half * 32;
    #pragma unroll
    for (int i = 0; i < 4; ++i) {
      const int cs = half * 4 + i;
      *(u16x8*)(dst + i * 8) = *(const u16x8*)(T + p * 64 + ((cs ^ (p & 7)) << 3));
    }
  } else {
    // emb2 (oc 256..383): NCHW f32 to d_out + y2 atomics + NHWC f32 to F2 via swizzled T [128px][64ch] f32
    #pragma unroll
    for (int mt = 0; mt < 4; ++mt)
      #pragma unroll
      for (int j = 0; j < 4; ++j) {
        const int ocl = (octile - 4) * 64 + mt * 16 + q4 + j;
        float* orow = out2 + ((size_t)(n * 128 + ocl)) * 4096 + (h0 + pxrow) * 64 + pxc0;
        orow[r0] = vals[mt][0][j];
        orow[16 + r0] = vals[mt][1][j];
      }
    if (n < 2) {
      #pragma unroll
      for (int nt = 0; nt < 2; ++nt) {
        float s = 0.f;
        #pragma unroll
        for (int mt = 0; mt < 4; ++mt)
          #pragma unroll
          for (int j = 0; j < 4; ++j) s = fmaf(vals[mt][nt][j], vals[mt][nt][j], s);
        s += __shfl_xor(s, 16);
        s += __shfl_xor(s, 32);
        if ((lane >> 4) == 0)
          atomicAdd(&Y2[(size_t)(n * 68 + h0 + pxrow + 2) * 68 + pxc0 + nt * 16 + r0 + 2], s);
      }
    }
    float* T = (float*)lds;  // 32KB
    #pragma unroll
    for (int mt = 0; mt < 4; ++mt)
      #pragma unroll
      for (int nt = 0; nt < 2; ++nt) {
        const int p = pxrow * 64 + pxc0 + nt * 16 + r0;
        #pragma unroll
        for (int j = 0; j < 4; ++j) {
          const int c = mt * 16 + q4 + j;
          T[p * 64 + (((c >> 2) ^ (p & 15)) << 2) + (c & 3)] = vals[mt][nt][j];
        }
      }
    __syncthreads();
    const int p = tid >> 1, half = tid & 1;
    float* dst = F2 + ((size_t)((n * 68 + h0 + (p >> 6) + 2) * 68 + (p & 63) + 2)) * 128 + (octile - 4) * 64 + half * 32;
    #pragma unroll
    for (int i = 0; i < 8; ++i) {
      const int cs = half * 8 + i;
      *(float4*)(dst + i * 4) = *(const float4*)(T + p * 64 + ((cs ^ (p & 15)) << 2));
    }
  }
}

// ---------------- fused distance + softmax + warp -> fea (16 lanes/px, L2-direct) ----------------
__global__ __launch_bounds__(256) void k_dw(const float* __restrict__ F2, const float* __restrict__ Y2,
                                            const u16* __restrict__ Fs, u16* __restrict__ Fea) {
  const int t = blockIdx.x * 256 + threadIdx.x;
  const int g = t & 15;
  const int px = t >> 4;
  const int n = px >> 12;
  const int p = px & 4095;
  const int h = p >> 6, w = p & 63;

  const float4* c2p = (const float4*)(F2 + ((size_t)(((n + 2) * 68 + h + 2) * 68 + (w + 2))) * 128 + g * 8);
  float4 c2v[2];
  float x2 = 0.f;
  #pragma unroll
  for (int i = 0; i < 2; ++i) {
    c2v[i] = c2p[i];
    x2 += c2v[i].x * c2v[i].x + c2v[i].y * c2v[i].y + c2v[i].z * c2v[i].z + c2v[i].w * c2v[i].w;
  }
  float cross[25];
  #pragma unroll
  for (int dy = 0; dy < 5; ++dy) {
    const float* rowp = F2 + ((size_t)((n * 68 + h + dy) * 68 + w)) * 128 + g * 8;
    #pragma unroll
    for (int dx = 0; dx < 5; ++dx) {
      const float4* wp = (const float4*)(rowp + dx * 128);
      float s = 0.f;
      #pragma unroll
      for (int i = 0; i < 2; ++i) {
        const float4 u = wp[i];
        s += c2v[i].x * u.x + c2v[i].y * u.y + c2v[i].z * u.z + c2v[i].w * u.w;
      }
      cross[dy * 5 + dx] = s;
    }
  }
  x2 += __shfl_xor(x2, 1); x2 += __shfl_xor(x2, 2); x2 += __shfl_xor(x2, 4); x2 += __shfl_xor(x2, 8);
  #pragma unroll
  for (int o = 0; o < 25; ++o) {
    cross[o] += __shfl_xor(cross[o], 1);
    cross[o] += __shfl_xor(cross[o], 2);
    cross[o] += __shfl_xor(cross[o], 4);
    cross[o] += __shfl_xor(cross[o], 8);
  }
  float wv[25], mx = -1e30f;
  #pragma unroll
  for (int dy = 0; dy < 5; ++dy)
    #pragma unroll
    for (int dx = 0; dx < 5; ++dx) {
      const int o = dy * 5 + dx;
      const float y2v = Y2[(size_t)(n * 68 + h + dy) * 68 + (w + dx)];
      const float dist = x2 + y2v - 2.f * cross[o];
      const float l = 1.f / (dist + 1e-5f);
      wv[o] = l;
      mx = fmaxf(mx, l);
    }
  float ssum = 0.f;
  #pragma unroll
  for (int o = 0; o < 25; ++o) { const float e = __expf(wv[o] - mx); wv[o] = e; ssum += e; }
  const float inv = 1.f / ssum;
  #pragma unroll
  for (int o = 0; o < 25; ++o) wv[o] *= inv;

  float facc[16];
  #pragma unroll
  for (int i = 0; i < 16; ++i) facc[i] = 0.f;
  #pragma unroll
  for (int dy = 0; dy < 5; ++dy) {
    const u16* rp = Fs + ((size_t)((n * 68 + h + dy) * 68 + w)) * 256 + g * 16;
    #pragma unroll
    for (int dx = 0; dx < 5; ++dx) {
      const float wt = wv[dy * 5 + dx];
      const u16x8* up = (const u16x8*)(rp + dx * 256);
      #pragma unroll
      for (int k = 0; k < 2; ++k) {
        const u16x8 u = up[k];
        #pragma unroll
        for (int j = 0; j < 8; ++j) facc[k * 8 + j] = fmaf(wt, bf2f(u[j]), facc[k * 8 + j]);
      }
    }
  }
  const u16x8* cip = (const u16x8*)(Fs + ((size_t)(((n + 2) * 68 + h + 2) * 68 + (w + 2))) * 256 + g * 16);
  u16x8* dp = (u16x8*)(Fea + ((size_t)(n * 4096 + p)) * 256 + g * 16);
  #pragma unroll
  for (int k = 0; k < 2; ++k) {
    const u16x8 cu = cip[k];
    u16x8 ou;
    #pragma unroll
    for (int j = 0; j < 8; ++j)
      ou[j] = f2bf(0.5f * (bf2f(cu[j]) + facc[k * 8 + j] * (1.f / 25.f)));
    dp[k] = ou;
  }
}

// ---------------- logits (124x256 via MFMA) + log_softmax ----------------
__global__ __launch_bounds__(128) void k_logits(const u16* __restrict__ Fea, const u16* __restrict__ Wl,
                                                const float* __restrict__ lb, float* __restrict__ xout) {
  const int wvi = threadIdx.x >> 6, lane = threadIdx.x & 63;
  const int wid = blockIdx.x * 2 + wvi;
  const int n = wid >> 8;
  const int p0 = (wid & 255) * 16;
  const int lp = lane & 15;
  const int kb = (lane >> 4) * 8;

  v4f acc[8];
  #pragma unroll
  for (int mt = 0; mt < 8; ++mt) acc[mt] = (v4f){0.f, 0.f, 0.f, 0.f};

  #pragma unroll
  for (int kc = 0; kc < 8; ++kc) {
    const v8bf b = *(const v8bf*)(Fea + ((size_t)(n * 4096 + p0 + lp)) * 256 + kc * 32 + kb);
    #pragma unroll
    for (int mt = 0; mt < 8; ++mt) {
      const v8bf a = *(const v8bf*)(Wl + ((size_t)(mt * 16 + lp)) * 256 + kc * 32 + kb);
      acc[mt] = __builtin_amdgcn_mfma_f32_16x16x32_bf16(a, b, acc[mt], 0, 0, 0);
    }
  }
  const int r0 = (lane >> 4) * 4;
  float v[8][4];
  float mx = -1e30f;
  #pragma unroll
  for (int mt = 0; mt < 8; ++mt)
    #pragma unroll
    for (int j = 0; j < 4; ++j) {
      const int cls = mt * 16 + r0 + j;
      const float val = (cls < 124) ? (acc[mt][j] + lb[cls]) : -1e30f;
      v[mt][j] = val;
      mx = fmaxf(mx, val);
    }
  mx = fmaxf(mx, __shfl_xor(mx, 16));
  mx = fmaxf(mx, __shfl_xor(mx, 32));
  float s = 0.f;
  #pragma unroll
  for (int mt = 0; mt < 8; ++mt)
    #pragma unroll
    for (int j = 0; j < 4; ++j) {
      const int cls = mt * 16 + r0 + j;
      if (cls < 124) s += __expf(v[mt][j] - mx);
    }
  s += __shfl_xor(s, 16);
  s += __shfl_xor(s, 32);
  const float lz = mx + logf(s);
  #pragma unroll
  for (int mt = 0; mt < 8; ++mt)
    #pragma unroll
    for (int j = 0; j < 4; ++j) {
      const int cls = mt * 16 + r0 + j;
      if (cls < 124)
        xout[((size_t)(n * 124 + cls)) * 4096 + p0 + lp] = v[mt][j] - lz;
    }
}

extern "C" void kernel_launch(void* const* d_in, const int* in_sizes, int n_in,
                              void* d_out, int out_size, void* d_ws, size_t ws_size,
                              hipStream_t stream) {
  (void)in_sizes; (void)n_in; (void)out_size;
  const float* clip  = (const float*)d_in[0];
  const float* embW  = (const float*)d_in[2];
  const float* eg    = (const float*)d_in[3];
  const float* eb    = (const float*)d_in[4];
  const float* em    = (const float*)d_in[5];
  const float* ev    = (const float*)d_in[6];
  const float* emb2W = (const float*)d_in[7];
  const float* e2g   = (const float*)d_in[8];
  const float* e2b   = (const float*)d_in[9];
  const float* e2m   = (const float*)d_in[10];
  const float* e2v   = (const float*)d_in[11];
  const float* lw    = (const float*)d_in[12];
  const float* lb    = (const float*)d_in[13];

  char* ws = (char*)d_ws;
  u16*   Xh  = (u16*)(ws + XH_OFF);
  u16*   Wf  = (u16*)(ws + WT_OFF);
  u16*   Fs  = (u16*)(ws + FS_OFF);
  float* F2  = (float*)(ws + F2_OFF);
  float* Y2  = (float*)(ws + Y2_OFF);
  u16*   Fea = (u16*)(ws + FEA_OFF);
  u16*   Wl  = (u16*)(ws + WL_OFF);
  float* sc  = (float*)(ws + SC_OFF);
  float* bi  = sc + 384;

  float* xout = (float*)d_out;
  float* out2 = xout + (size_t)2 * 124 * 64 * 64;

  if (ws_size < WS_TOTAL) return;

  k_prep<<<1152, 256, 0, stream>>>(clip, embW, emb2W, eg, eb, em, ev, e2g, e2b, e2m, e2v, lw,
                                   Xh, Wf, Fs, F2, Y2, Wl, sc, bi);
  k_conv<<<768, 256, 0, stream>>>(Xh, Wf, sc, bi, out2, F2, Fs, Y2);
  k_dw<<<512, 256, 0, stream>>>(F2, Y2, Fs, Fea);
  k_logits<<<256, 128, 0, stream>>>(Fea, Wl, lb, xout);
}